// Round 3
// baseline (1421.779 us; speedup 1.0000x reference)
//
#include <hip/hip_runtime.h>

#define NN 100000
#define EE 1600000
#define FIN 64
#define HH 128
#define GG 512
#define EPSV 1e-5f

// ---------------- init ----------------
__global__ void initk(int* deg, int* cursor, int* counts,
                      float* gsum1, float* gsq1, float* gsum2, float* gsq2,
                      float* pooled) {
  int i = blockIdx.x * 256 + threadIdx.x;
  if (i < NN) { deg[i] = 1; cursor[i] = 0; }          // self-loop contributes 1
  if (i < GG) { counts[i] = 0; gsum1[i] = 0.f; gsq1[i] = 0.f; gsum2[i] = 0.f; gsq2[i] = 0.f; }
  if (i < GG * HH) pooled[i] = 0.f;
}

// ---------------- degree + graph counts ----------------
__global__ void countk(const int* __restrict__ ei, const int* __restrict__ batch,
                       int* deg, int* counts) {
  int i = blockIdx.x * 256 + threadIdx.x;
  if (i < EE) atomicAdd(&deg[ei[EE + i]], 1);   // dst row of edge_index
  if (i < NN) atomicAdd(&counts[batch[i]], 1);
}

__global__ void disk(const int* __restrict__ deg, float* __restrict__ dis) {
  int i = blockIdx.x * 256 + threadIdx.x;
  if (i < NN) dis[i] = rsqrtf((float)deg[i]);   // deg >= 1 always (self loop)
}

// ---------------- exclusive scan of in-degree (deg-1) -> rowptr ----------------
#define SCHUNK 1024
__global__ void scan1(const int* __restrict__ deg, int* __restrict__ bsum) {
  __shared__ int red[256];
  int b = blockIdx.x, t = threadIdx.x;
  int base = b * SCHUNK + t * 4;
  int s = 0;
#pragma unroll
  for (int i = 0; i < 4; i++) { int idx = base + i; if (idx < NN) s += deg[idx] - 1; }
  red[t] = s; __syncthreads();
  for (int o = 128; o > 0; o >>= 1) { if (t < o) red[t] += red[t + o]; __syncthreads(); }
  if (t == 0) bsum[b] = red[0];
}

__global__ void scan2(const int* __restrict__ bsum, int* __restrict__ boff,
                      int* __restrict__ rowptr, int nblk) {
  if (threadIdx.x == 0 && blockIdx.x == 0) {
    int run = 0;
    for (int i = 0; i < nblk; i++) { boff[i] = run; run += bsum[i]; }
    rowptr[NN] = run;  // == EE
  }
}

__global__ void scan3(const int* __restrict__ deg, const int* __restrict__ boff,
                      int* __restrict__ rowptr) {
  __shared__ int sc[2][256];
  int b = blockIdx.x, t = threadIdx.x;
  int base = b * SCHUNK + t * 4;
  int v[4]; int s = 0;
#pragma unroll
  for (int i = 0; i < 4; i++) {
    int idx = base + i;
    v[i] = (idx < NN) ? (deg[idx] - 1) : 0;
    s += v[i];
  }
  int pp = 0;
  sc[0][t] = s; __syncthreads();
  for (int o = 1; o < 256; o <<= 1) {
    int val = sc[pp][t];
    if (t >= o) val += sc[pp][t - o];
    sc[pp ^ 1][t] = val; __syncthreads();
    pp ^= 1;
  }
  int excl = sc[pp][t] - s;
  int p = boff[b] + excl;
#pragma unroll
  for (int i = 0; i < 4; i++) {
    int idx = base + i;
    if (idx < NN) rowptr[idx] = p;
    p += v[i];
  }
}

__global__ void scatterk(const int* __restrict__ ei, int* cursor,
                         const int* __restrict__ rowptr, int* __restrict__ colsrc) {
  int e = blockIdx.x * 256 + threadIdx.x;
  if (e >= EE) return;
  int d = ei[EE + e];
  int pos = rowptr[d] + atomicAdd(&cursor[d], 1);
  colsrc[pos] = ei[e];
}

// ---------------- fc1: [N,64] @ [64,128] + b ----------------
__global__ void gemm64(const float* __restrict__ X, const float* __restrict__ W,
                       const float* __restrict__ bias, float* __restrict__ Y) {
  __shared__ float xs[8 * 64];
  int n0 = blockIdx.x * 8, t = threadIdx.x;
  const float* xb = X + (size_t)n0 * 64;
  for (int i = t; i < 512; i += 128) xs[i] = xb[i];
  __syncthreads();
  float bv = bias[t];
  float acc[8];
#pragma unroll
  for (int n = 0; n < 8; n++) acc[n] = bv;
#pragma unroll 4
  for (int k = 0; k < 64; k++) {
    float wv = W[k * 128 + t];
#pragma unroll
    for (int n = 0; n < 8; n++) acc[n] = fmaf(xs[n * 64 + k], wv, acc[n]);
  }
#pragma unroll
  for (int n = 0; n < 8; n++) Y[(size_t)(n0 + n) * 128 + t] = acc[n];
}

// ---------------- [N,128] @ [128,128], optional fused graph-LN + ReLU on load ----------------
template <bool LN>
__global__ void gemm128(const float* __restrict__ X, const float* __restrict__ W,
                        float* __restrict__ Y,
                        const int* __restrict__ batch,
                        const float* __restrict__ mean, const float* __restrict__ inv,
                        const float* __restrict__ gamma, const float* __restrict__ beta) {
  __shared__ float xs[8 * 128];
  int n0 = blockIdx.x * 8, t = threadIdx.x;
  const float* xb = X + (size_t)n0 * 128;
  if (LN) {
#pragma unroll
    for (int j = 0; j < 8; j++) {
      int node = n0 + j;
      int bb = batch[node];
      float v = xb[j * 128 + t];
      v = (v - mean[bb]) * inv[bb] * gamma[t] + beta[t];
      xs[j * 128 + t] = fmaxf(v, 0.f);
    }
  } else {
    for (int i = t; i < 1024; i += 128) xs[i] = xb[i];
  }
  __syncthreads();
  float acc[8];
#pragma unroll
  for (int n = 0; n < 8; n++) acc[n] = 0.f;
#pragma unroll 4
  for (int k = 0; k < 128; k++) {
    float wv = W[k * 128 + t];
#pragma unroll
    for (int n = 0; n < 8; n++) acc[n] = fmaf(xs[n * 128 + k], wv, acc[n]);
  }
#pragma unroll
  for (int n = 0; n < 8; n++) Y[(size_t)(n0 + n) * 128 + t] = acc[n];
}

// ---------------- CSR aggregation + bias, fused per-graph stats ----------------
__global__ void aggk(const float* __restrict__ Hin, const int* __restrict__ colsrc,
                     const int* __restrict__ rowptr, const float* __restrict__ dis,
                     const float* __restrict__ bias, const int* __restrict__ batch,
                     float* __restrict__ Yout, float* gsum, float* gsq) {
  int n = blockIdx.x, t = threadIdx.x;  // 128 threads: one channel each
  float di = dis[n];
  float acc = Hin[(size_t)n * 128 + t] * di * di;  // self loop
  int rp0 = rowptr[n], rp1 = rowptr[n + 1];
  int e = rp0;
  for (; e + 1 < rp1; e += 2) {
    int s0 = colsrc[e], s1 = colsrc[e + 1];
    float w0 = dis[s0] * di, w1 = dis[s1] * di;
    float h0 = Hin[(size_t)s0 * 128 + t];
    float h1 = Hin[(size_t)s1 * 128 + t];
    acc = fmaf(h0, w0, acc);
    acc = fmaf(h1, w1, acc);
  }
  if (e < rp1) {
    int s0 = colsrc[e];
    acc = fmaf(Hin[(size_t)s0 * 128 + t], dis[s0] * di, acc);
  }
  acc += bias[t];
  Yout[(size_t)n * 128 + t] = acc;
  // fused per-graph stats
  float s1v = acc, s2v = acc * acc;
  for (int o = 32; o > 0; o >>= 1) {
    s1v += __shfl_down(s1v, o);
    s2v += __shfl_down(s2v, o);
  }
  __shared__ float l1[2], l2[2];
  int wid = t >> 6, lane = t & 63;
  if (lane == 0) { l1[wid] = s1v; l2[wid] = s2v; }
  __syncthreads();
  if (t == 0) {
    int b = batch[n];
    atomicAdd(&gsum[b], l1[0] + l1[1]);
    atomicAdd(&gsq[b], l2[0] + l2[1]);
  }
}

__global__ void lnfinal(const float* __restrict__ gsum, const float* __restrict__ gsq,
                        const int* __restrict__ counts,
                        float* __restrict__ mean, float* __restrict__ inv) {
  int g = blockIdx.x * 256 + threadIdx.x;
  if (g >= GG) return;
  float denom = fmaxf((float)counts[g] * (float)HH, 1.f);
  float m = gsum[g] / denom;
  float v = gsq[g] / denom - m * m;
  mean[g] = m;
  inv[g] = rsqrtf(fmaxf(v, 0.f) + EPSV);
}

// ---------------- LN2 + ReLU + mean-pool scatter ----------------
__global__ void poolk(const float* __restrict__ A, const int* __restrict__ batch,
                      const float* __restrict__ mean, const float* __restrict__ inv,
                      const float* __restrict__ gamma, const float* __restrict__ beta,
                      float* __restrict__ pooled) {
  int idx = blockIdx.x * 256 + threadIdx.x;
  if (idx >= NN * HH) return;
  int n = idx >> 7, ch = idx & 127;
  int b = batch[n];
  float v = (A[idx] - mean[b]) * inv[b] * gamma[ch] + beta[ch];
  v = fmaxf(v, 0.f);
  atomicAdd(&pooled[b * 128 + ch], v);
}

__global__ void finalk(const float* __restrict__ pooled, const int* __restrict__ counts,
                       const float* __restrict__ w, const float* __restrict__ b,
                       float* __restrict__ out) {
  int g = blockIdx.x, t = threadIdx.x;  // 128 threads
  float cnt = fmaxf((float)counts[g], 1.f);
  float v = pooled[g * 128 + t] / cnt * w[t];
  for (int o = 32; o > 0; o >>= 1) v += __shfl_down(v, o);
  __shared__ float l[2];
  if ((t & 63) == 0) l[t >> 6] = v;
  __syncthreads();
  if (t == 0) out[g] = l[0] + l[1] + b[0];
}

extern "C" void kernel_launch(void* const* d_in, const int* in_sizes, int n_in,
                              void* d_out, int out_size, void* d_ws, size_t ws_size,
                              hipStream_t stream) {
  const float* x = (const float*)d_in[0];
  const int* ei = (const int*)d_in[1];      // [2,E] flat; src = ei[0..E), dst = ei[E..2E)
  const int* batch = (const int*)d_in[2];
  const float* fc1_w = (const float*)d_in[3];
  const float* fc1_b = (const float*)d_in[4];
  const float* gc1_w = (const float*)d_in[5];
  const float* gc1_b = (const float*)d_in[6];
  const float* gn1_g = (const float*)d_in[7];
  const float* gn1_b = (const float*)d_in[8];
  const float* gc2_w = (const float*)d_in[9];
  const float* gc2_b = (const float*)d_in[10];
  const float* gn2_g = (const float*)d_in[11];
  const float* gn2_b = (const float*)d_in[12];
  const float* fc2_w = (const float*)d_in[13];
  const float* fc2_b = (const float*)d_in[14];
  float* out = (float*)d_out;

  char* p = (char*)d_ws;
  auto alloc = [&](size_t bytes) { void* r = (void*)p; p += ((bytes + 255) / 256) * 256; return r; };
  float* A = (float*)alloc((size_t)NN * HH * 4);
  float* B = (float*)alloc((size_t)NN * HH * 4);
  int* colsrc = (int*)alloc((size_t)EE * 4);
  int* rowptr = (int*)alloc((size_t)(NN + 1) * 4);
  int* deg = (int*)alloc((size_t)NN * 4);
  int* cursor = (int*)alloc((size_t)NN * 4);
  float* dis = (float*)alloc((size_t)NN * 4);
  int* counts = (int*)alloc((size_t)GG * 4);
  float* gsum1 = (float*)alloc((size_t)GG * 4);
  float* gsq1 = (float*)alloc((size_t)GG * 4);
  float* gsum2 = (float*)alloc((size_t)GG * 4);
  float* gsq2 = (float*)alloc((size_t)GG * 4);
  float* mean1 = (float*)alloc((size_t)GG * 4);
  float* inv1 = (float*)alloc((size_t)GG * 4);
  float* mean2 = (float*)alloc((size_t)GG * 4);
  float* inv2 = (float*)alloc((size_t)GG * 4);
  float* pooled = (float*)alloc((size_t)GG * HH * 4);
  int* bsum = (int*)alloc(1024);
  int* boff = (int*)alloc(1024);

  int nblk = (NN + SCHUNK - 1) / SCHUNK;

  initk<<<(NN + 255) / 256, 256, 0, stream>>>(deg, cursor, counts, gsum1, gsq1, gsum2, gsq2, pooled);
  countk<<<(EE + 255) / 256, 256, 0, stream>>>(ei, batch, deg, counts);
  disk<<<(NN + 255) / 256, 256, 0, stream>>>(deg, dis);
  scan1<<<nblk, 256, 0, stream>>>(deg, bsum);
  scan2<<<1, 64, 0, stream>>>(bsum, boff, rowptr, nblk);
  scan3<<<nblk, 256, 0, stream>>>(deg, boff, rowptr);
  scatterk<<<(EE + 255) / 256, 256, 0, stream>>>(ei, cursor, rowptr, colsrc);

  gemm64<<<NN / 8, 128, 0, stream>>>(x, fc1_w, fc1_b, A);
  gemm128<false><<<NN / 8, 128, 0, stream>>>(A, gc1_w, B, nullptr, nullptr, nullptr, nullptr, nullptr);
  aggk<<<NN, 128, 0, stream>>>(B, colsrc, rowptr, dis, gc1_b, batch, A, gsum1, gsq1);
  lnfinal<<<(GG + 255) / 256, 256, 0, stream>>>(gsum1, gsq1, counts, mean1, inv1);
  gemm128<true><<<NN / 8, 128, 0, stream>>>(A, gc2_w, B, batch, mean1, inv1, gn1_g, gn1_b);
  aggk<<<NN, 128, 0, stream>>>(B, colsrc, rowptr, dis, gc2_b, batch, A, gsum2, gsq2);
  lnfinal<<<(GG + 255) / 256, 256, 0, stream>>>(gsum2, gsq2, counts, mean2, inv2);
  poolk<<<(NN * HH + 255) / 256, 256, 0, stream>>>(A, batch, mean2, inv2, gn2_g, gn2_b, pooled);
  finalk<<<GG, 128, 0, stream>>>(pooled, counts, fc2_w, fc2_b, out);
}

// Round 7
// 1094.069 us; speedup vs baseline: 1.2995x; 1.2995x over previous
//
#include <hip/hip_runtime.h>

#define NN 100000
#define EE 1600000
#define FIN 64
#define HH 128
#define GG 512
#define EPSV 1e-5f

// ---------------- init ----------------
__global__ void initk(int* deg, int* cursor, int* counts,
                      float* gsum1, float* gsq1, float* gsum2, float* gsq2,
                      float* pooled) {
  int i = blockIdx.x * 256 + threadIdx.x;
  if (i < NN) { deg[i] = 1; cursor[i] = 0; }          // self-loop contributes 1
  if (i < GG) { counts[i] = 0; gsum1[i] = 0.f; gsq1[i] = 0.f; gsum2[i] = 0.f; gsq2[i] = 0.f; }
  if (i < GG * HH) pooled[i] = 0.f;
}

// ---------------- degree + graph counts ----------------
__global__ void countk(const int* __restrict__ ei, const int* __restrict__ batch,
                       int* deg, int* counts) {
  int i = blockIdx.x * 256 + threadIdx.x;
  if (i < EE) atomicAdd(&deg[ei[EE + i]], 1);   // dst row of edge_index
  if (i < NN) atomicAdd(&counts[batch[i]], 1);
}

__global__ void disk(const int* __restrict__ deg, float* __restrict__ dis) {
  int i = blockIdx.x * 256 + threadIdx.x;
  if (i < NN) dis[i] = rsqrtf((float)deg[i]);   // deg >= 1 always (self loop)
}

// ---------------- exclusive scan of in-degree (deg-1) -> rowptr ----------------
#define SCHUNK 1024
__global__ void scan1(const int* __restrict__ deg, int* __restrict__ bsum) {
  __shared__ int red[256];
  int b = blockIdx.x, t = threadIdx.x;
  int base = b * SCHUNK + t * 4;
  int s = 0;
#pragma unroll
  for (int i = 0; i < 4; i++) { int idx = base + i; if (idx < NN) s += deg[idx] - 1; }
  red[t] = s; __syncthreads();
  for (int o = 128; o > 0; o >>= 1) { if (t < o) red[t] += red[t + o]; __syncthreads(); }
  if (t == 0) bsum[b] = red[0];
}

__global__ void scan2(const int* __restrict__ bsum, int* __restrict__ boff,
                      int* __restrict__ rowptr, int nblk) {
  if (threadIdx.x == 0 && blockIdx.x == 0) {
    int run = 0;
    for (int i = 0; i < nblk; i++) { boff[i] = run; run += bsum[i]; }
    rowptr[NN] = run;  // == EE
  }
}

__global__ void scan3(const int* __restrict__ deg, const int* __restrict__ boff,
                      int* __restrict__ rowptr) {
  __shared__ int sc[2][256];
  int b = blockIdx.x, t = threadIdx.x;
  int base = b * SCHUNK + t * 4;
  int v[4]; int s = 0;
#pragma unroll
  for (int i = 0; i < 4; i++) {
    int idx = base + i;
    v[i] = (idx < NN) ? (deg[idx] - 1) : 0;
    s += v[i];
  }
  int pp = 0;
  sc[0][t] = s; __syncthreads();
  for (int o = 1; o < 256; o <<= 1) {
    int val = sc[pp][t];
    if (t >= o) val += sc[pp][t - o];
    sc[pp ^ 1][t] = val; __syncthreads();
    pp ^= 1;
  }
  int excl = sc[pp][t] - s;
  int p = boff[b] + excl;
#pragma unroll
  for (int i = 0; i < 4; i++) {
    int idx = base + i;
    if (idx < NN) rowptr[idx] = p;
    p += v[i];
  }
}

__global__ void scatterk(const int* __restrict__ ei, int* cursor,
                         const int* __restrict__ rowptr, int* __restrict__ colsrc) {
  int e = blockIdx.x * 256 + threadIdx.x;
  if (e >= EE) return;
  int d = ei[EE + e];
  int pos = rowptr[d] + atomicAdd(&cursor[d], 1);
  colsrc[pos] = ei[e];
}

// ---------------- fc1: [N,64] @ [64,128] + b ----------------
__global__ void gemm64(const float* __restrict__ X, const float* __restrict__ W,
                       const float* __restrict__ bias, float* __restrict__ Y) {
  __shared__ float xs[8 * 64];
  int n0 = blockIdx.x * 8, t = threadIdx.x;
  const float* xb = X + (size_t)n0 * 64;
  for (int i = t; i < 512; i += 128) xs[i] = xb[i];
  __syncthreads();
  float bv = bias[t];
  float acc[8];
#pragma unroll
  for (int n = 0; n < 8; n++) acc[n] = bv;
#pragma unroll 4
  for (int k = 0; k < 64; k++) {
    float wv = W[k * 128 + t];
#pragma unroll
    for (int n = 0; n < 8; n++) acc[n] = fmaf(xs[n * 64 + k], wv, acc[n]);
  }
#pragma unroll
  for (int n = 0; n < 8; n++) Y[(size_t)(n0 + n) * 128 + t] = acc[n];
}

// ---------------- [N,128] @ [128,128], optional fused graph-LN + ReLU on load ----------------
template <bool LN>
__global__ void gemm128(const float* __restrict__ X, const float* __restrict__ W,
                        float* __restrict__ Y,
                        const int* __restrict__ batch,
                        const float* __restrict__ mean, const float* __restrict__ inv,
                        const float* __restrict__ gamma, const float* __restrict__ beta) {
  __shared__ float xs[8 * 128];
  int n0 = blockIdx.x * 8, t = threadIdx.x;
  const float* xb = X + (size_t)n0 * 128;
  if (LN) {
#pragma unroll
    for (int j = 0; j < 8; j++) {
      int node = n0 + j;
      int bb = batch[node];
      float v = xb[j * 128 + t];
      v = (v - mean[bb]) * inv[bb] * gamma[t] + beta[t];
      xs[j * 128 + t] = fmaxf(v, 0.f);
    }
  } else {
    for (int i = t; i < 1024; i += 128) xs[i] = xb[i];
  }
  __syncthreads();
  float acc[8];
#pragma unroll
  for (int n = 0; n < 8; n++) acc[n] = 0.f;
#pragma unroll 4
  for (int k = 0; k < 128; k++) {
    float wv = W[k * 128 + t];
#pragma unroll
    for (int n = 0; n < 8; n++) acc[n] = fmaf(xs[n * 128 + k], wv, acc[n]);
  }
#pragma unroll
  for (int n = 0; n < 8; n++) Y[(size_t)(n0 + n) * 128 + t] = acc[n];
}

// ---------------- CSR aggregation + bias, fused per-graph stats ----------------
// One wave per node. Lane layout: half = lane>>5 (edge slot within a pair),
// q = lane&31 (16B chunk of the 512B row). Each lane loads float4; a wave
// covers 2 rows per load instruction; unroll x4 => 8 edges / 4 independent
// 1KB loads in flight. Self-loop folded in as virtual edge index m-1.
__global__ __launch_bounds__(256, 8)
void aggk(const float* __restrict__ Hin, const int* __restrict__ colsrc,
          const int* __restrict__ rowptr, const float* __restrict__ dis,
          const float* __restrict__ bias, const int* __restrict__ batch,
          float* __restrict__ Yout, float* __restrict__ gsum, float* __restrict__ gsq) {
  int wid = threadIdx.x >> 6;
  int n = blockIdx.x * 4 + wid;          // NN % 4 == 0, always valid
  int lane = threadIdx.x & 63;
  int half = lane >> 5, q = lane & 31;
  float di = dis[n];
  int rp0 = rowptr[n];
  int m = rowptr[n + 1] - rp0 + 1;       // edges + self (self at index m-1)
  float4 acc = make_float4(0.f, 0.f, 0.f, 0.f);
  int p = 0;
  for (; p + 7 < m; p += 8) {
    int s[4]; float w[4]; float4 h[4];
#pragma unroll
    for (int j = 0; j < 4; j++) {
      int idx = p + 2 * j + half;
      s[j] = (idx == m - 1) ? n : colsrc[rp0 + idx];
    }
#pragma unroll
    for (int j = 0; j < 4; j++) {
      w[j] = dis[s[j]] * di;
      h[j] = *reinterpret_cast<const float4*>(&Hin[(size_t)s[j] * HH + q * 4]);
    }
#pragma unroll
    for (int j = 0; j < 4; j++) {
      acc.x = fmaf(h[j].x, w[j], acc.x);
      acc.y = fmaf(h[j].y, w[j], acc.y);
      acc.z = fmaf(h[j].z, w[j], acc.z);
      acc.w = fmaf(h[j].w, w[j], acc.w);
    }
  }
  for (; p < m; p += 2) {
    int idx = p + half;
    if (idx < m) {
      int s = (idx == m - 1) ? n : colsrc[rp0 + idx];
      float w = dis[s] * di;
      float4 h = *reinterpret_cast<const float4*>(&Hin[(size_t)s * HH + q * 4]);
      acc.x = fmaf(h.x, w, acc.x);
      acc.y = fmaf(h.y, w, acc.y);
      acc.z = fmaf(h.z, w, acc.z);
      acc.w = fmaf(h.w, w, acc.w);
    }
  }
  // merge the two halves (lane l <-> lane l^32); both halves end up with full sums
  acc.x += __shfl_xor(acc.x, 32);
  acc.y += __shfl_xor(acc.y, 32);
  acc.z += __shfl_xor(acc.z, 32);
  acc.w += __shfl_xor(acc.w, 32);
  float4 bv = *reinterpret_cast<const float4*>(&bias[q * 4]);
  acc.x += bv.x; acc.y += bv.y; acc.z += bv.z; acc.w += bv.w;
  if (half == 0) {
    *reinterpret_cast<float4*>(&Yout[(size_t)n * HH + q * 4]) = acc;
  }
  // per-wave stats over lanes 0..31 (each channel once)
  float s1 = acc.x + acc.y + acc.z + acc.w;
  float s2 = acc.x * acc.x + acc.y * acc.y + acc.z * acc.z + acc.w * acc.w;
  for (int o = 16; o > 0; o >>= 1) {
    s1 += __shfl_down(s1, o);
    s2 += __shfl_down(s2, o);
  }
  if (lane == 0) {
    int b = batch[n];
    atomicAdd(&gsum[b], s1);
    atomicAdd(&gsq[b], s2);
  }
}

__global__ void lnfinal(const float* __restrict__ gsum, const float* __restrict__ gsq,
                        const int* __restrict__ counts,
                        float* __restrict__ mean, float* __restrict__ inv) {
  int g = blockIdx.x * 256 + threadIdx.x;
  if (g >= GG) return;
  float denom = fmaxf((float)counts[g] * (float)HH, 1.f);
  float m = gsum[g] / denom;
  float v = gsq[g] / denom - m * m;
  mean[g] = m;
  inv[g] = rsqrtf(fmaxf(v, 0.f) + EPSV);
}

// ---------------- LN2 + ReLU + mean-pool scatter ----------------
__global__ void poolk(const float* __restrict__ A, const int* __restrict__ batch,
                      const float* __restrict__ mean, const float* __restrict__ inv,
                      const float* __restrict__ gamma, const float* __restrict__ beta,
                      float* __restrict__ pooled) {
  int idx = blockIdx.x * 256 + threadIdx.x;
  if (idx >= NN * HH) return;
  int n = idx >> 7, ch = idx & 127;
  int b = batch[n];
  float v = (A[idx] - mean[b]) * inv[b] * gamma[ch] + beta[ch];
  v = fmaxf(v, 0.f);
  atomicAdd(&pooled[b * 128 + ch], v);
}

__global__ void finalk(const float* __restrict__ pooled, const int* __restrict__ counts,
                       const float* __restrict__ w, const float* __restrict__ b,
                       float* __restrict__ out) {
  int g = blockIdx.x, t = threadIdx.x;  // 128 threads
  float cnt = fmaxf((float)counts[g], 1.f);
  float v = pooled[g * 128 + t] / cnt * w[t];
  for (int o = 32; o > 0; o >>= 1) v += __shfl_down(v, o);
  __shared__ float l[2];
  if ((t & 63) == 0) l[t >> 6] = v;
  __syncthreads();
  if (t == 0) out[g] = l[0] + l[1] + b[0];
}

extern "C" void kernel_launch(void* const* d_in, const int* in_sizes, int n_in,
                              void* d_out, int out_size, void* d_ws, size_t ws_size,
                              hipStream_t stream) {
  const float* x = (const float*)d_in[0];
  const int* ei = (const int*)d_in[1];      // [2,E] flat; src = ei[0..E), dst = ei[E..2E)
  const int* batch = (const int*)d_in[2];
  const float* fc1_w = (const float*)d_in[3];
  const float* fc1_b = (const float*)d_in[4];
  const float* gc1_w = (const float*)d_in[5];
  const float* gc1_b = (const float*)d_in[6];
  const float* gn1_g = (const float*)d_in[7];
  const float* gn1_b = (const float*)d_in[8];
  const float* gc2_w = (const float*)d_in[9];
  const float* gc2_b = (const float*)d_in[10];
  const float* gn2_g = (const float*)d_in[11];
  const float* gn2_b = (const float*)d_in[12];
  const float* fc2_w = (const float*)d_in[13];
  const float* fc2_b = (const float*)d_in[14];
  float* out = (float*)d_out;

  char* p = (char*)d_ws;
  auto alloc = [&](size_t bytes) { void* r = (void*)p; p += ((bytes + 255) / 256) * 256; return r; };
  float* A = (float*)alloc((size_t)NN * HH * 4);
  float* B = (float*)alloc((size_t)NN * HH * 4);
  int* colsrc = (int*)alloc((size_t)EE * 4);
  int* rowptr = (int*)alloc((size_t)(NN + 1) * 4);
  int* deg = (int*)alloc((size_t)NN * 4);
  int* cursor = (int*)alloc((size_t)NN * 4);
  float* dis = (float*)alloc((size_t)NN * 4);
  int* counts = (int*)alloc((size_t)GG * 4);
  float* gsum1 = (float*)alloc((size_t)GG * 4);
  float* gsq1 = (float*)alloc((size_t)GG * 4);
  float* gsum2 = (float*)alloc((size_t)GG * 4);
  float* gsq2 = (float*)alloc((size_t)GG * 4);
  float* mean1 = (float*)alloc((size_t)GG * 4);
  float* inv1 = (float*)alloc((size_t)GG * 4);
  float* mean2 = (float*)alloc((size_t)GG * 4);
  float* inv2 = (float*)alloc((size_t)GG * 4);
  float* pooled = (float*)alloc((size_t)GG * HH * 4);
  int* bsum = (int*)alloc(1024);
  int* boff = (int*)alloc(1024);

  int nblk = (NN + SCHUNK - 1) / SCHUNK;

  initk<<<(NN + 255) / 256, 256, 0, stream>>>(deg, cursor, counts, gsum1, gsq1, gsum2, gsq2, pooled);
  countk<<<(EE + 255) / 256, 256, 0, stream>>>(ei, batch, deg, counts);
  disk<<<(NN + 255) / 256, 256, 0, stream>>>(deg, dis);
  scan1<<<nblk, 256, 0, stream>>>(deg, bsum);
  scan2<<<1, 64, 0, stream>>>(bsum, boff, rowptr, nblk);
  scan3<<<nblk, 256, 0, stream>>>(deg, boff, rowptr);
  scatterk<<<(EE + 255) / 256, 256, 0, stream>>>(ei, cursor, rowptr, colsrc);

  gemm64<<<NN / 8, 128, 0, stream>>>(x, fc1_w, fc1_b, A);
  gemm128<false><<<NN / 8, 128, 0, stream>>>(A, gc1_w, B, nullptr, nullptr, nullptr, nullptr, nullptr);
  aggk<<<NN / 4, 256, 0, stream>>>(B, colsrc, rowptr, dis, gc1_b, batch, A, gsum1, gsq1);
  lnfinal<<<(GG + 255) / 256, 256, 0, stream>>>(gsum1, gsq1, counts, mean1, inv1);
  gemm128<true><<<NN / 8, 128, 0, stream>>>(A, gc2_w, B, batch, mean1, inv1, gn1_g, gn1_b);
  aggk<<<NN / 4, 256, 0, stream>>>(B, colsrc, rowptr, dis, gc2_b, batch, A, gsum2, gsq2);
  lnfinal<<<(GG + 255) / 256, 256, 0, stream>>>(gsum2, gsq2, counts, mean2, inv2);
  poolk<<<(NN * HH + 255) / 256, 256, 0, stream>>>(A, batch, mean2, inv2, gn2_g, gn2_b, pooled);
  finalk<<<GG, 128, 0, stream>>>(pooled, counts, fc2_w, fc2_b, out);
}

// Round 8
// 1039.695 us; speedup vs baseline: 1.3675x; 1.0523x over previous
//
#include <hip/hip_runtime.h>

#define NN 100000
#define EE 1600000
#define FIN 64
#define HH 128
#define GG 512
#define EPSV 1e-5f

// ---------------- init ----------------
__global__ void initk(int* deg, int* cursor, int* counts,
                      float* gsum1, float* gsq1, float* gsum2, float* gsq2,
                      float* pooled) {
  int i = blockIdx.x * 256 + threadIdx.x;
  if (i < NN) { deg[i] = 1; cursor[i] = 0; }          // self-loop contributes 1
  if (i < GG) { counts[i] = 0; gsum1[i] = 0.f; gsq1[i] = 0.f; gsum2[i] = 0.f; gsq2[i] = 0.f; }
  if (i < GG * HH) pooled[i] = 0.f;
}

// ---------------- degree + graph counts ----------------
__global__ void countk(const int* __restrict__ ei, const int* __restrict__ batch,
                       int* deg, int* counts) {
  int i = blockIdx.x * 256 + threadIdx.x;
  if (i < EE) atomicAdd(&deg[ei[EE + i]], 1);   // dst row of edge_index
  if (i < NN) atomicAdd(&counts[batch[i]], 1);
}

__global__ void disk(const int* __restrict__ deg, float* __restrict__ dis) {
  int i = blockIdx.x * 256 + threadIdx.x;
  if (i < NN) dis[i] = rsqrtf((float)deg[i]);   // deg >= 1 always (self loop)
}

// ---------------- exclusive scan of in-degree (deg-1) -> rowptr ----------------
#define SCHUNK 1024
__global__ void scan1(const int* __restrict__ deg, int* __restrict__ bsum) {
  __shared__ int red[256];
  int b = blockIdx.x, t = threadIdx.x;
  int base = b * SCHUNK + t * 4;
  int s = 0;
#pragma unroll
  for (int i = 0; i < 4; i++) { int idx = base + i; if (idx < NN) s += deg[idx] - 1; }
  red[t] = s; __syncthreads();
  for (int o = 128; o > 0; o >>= 1) { if (t < o) red[t] += red[t + o]; __syncthreads(); }
  if (t == 0) bsum[b] = red[0];
}

__global__ void scan2(const int* __restrict__ bsum, int* __restrict__ boff,
                      int* __restrict__ rowptr, int nblk) {
  if (threadIdx.x == 0 && blockIdx.x == 0) {
    int run = 0;
    for (int i = 0; i < nblk; i++) { boff[i] = run; run += bsum[i]; }
    rowptr[NN] = run;  // == EE
  }
}

__global__ void scan3(const int* __restrict__ deg, const int* __restrict__ boff,
                      int* __restrict__ rowptr) {
  __shared__ int sc[2][256];
  int b = blockIdx.x, t = threadIdx.x;
  int base = b * SCHUNK + t * 4;
  int v[4]; int s = 0;
#pragma unroll
  for (int i = 0; i < 4; i++) {
    int idx = base + i;
    v[i] = (idx < NN) ? (deg[idx] - 1) : 0;
    s += v[i];
  }
  int pp = 0;
  sc[0][t] = s; __syncthreads();
  for (int o = 1; o < 256; o <<= 1) {
    int val = sc[pp][t];
    if (t >= o) val += sc[pp][t - o];
    sc[pp ^ 1][t] = val; __syncthreads();
    pp ^= 1;
  }
  int excl = sc[pp][t] - s;
  int p = boff[b] + excl;
#pragma unroll
  for (int i = 0; i < 4; i++) {
    int idx = base + i;
    if (idx < NN) rowptr[idx] = p;
    p += v[i];
  }
}

__global__ void scatterk(const int* __restrict__ ei, int* cursor,
                         const int* __restrict__ rowptr, int* __restrict__ colsrc) {
  int e = blockIdx.x * 256 + threadIdx.x;
  if (e >= EE) return;
  int d = ei[EE + e];
  int pos = rowptr[d] + atomicAdd(&cursor[d], 1);
  colsrc[pos] = ei[e];
}

// ---------------- fold fc1 into gc1: Wp = fc1_w @ gc1_w  [64,128]; c1 = fc1_b @ gc1_w ----------------
__global__ void prepw(const float* __restrict__ fc1w, const float* __restrict__ fc1b,
                      const float* __restrict__ gc1w,
                      float* __restrict__ Wp, float* __restrict__ c1) {
  int k = blockIdx.x, t = threadIdx.x;
  if (k < 64) {
    float s = 0.f;
    for (int j = 0; j < 128; j++) s = fmaf(fc1w[k * 128 + j], gc1w[j * 128 + t], s);
    Wp[k * 128 + t] = s;
  } else {
    float s = 0.f;
    for (int j = 0; j < 128; j++) s = fmaf(fc1b[j], gc1w[j * 128 + t], s);
    c1[t] = s;
  }
}

// ---------------- layer-1 aggregation on raw x (64-wide) + rowsum ----------------
// One wave per node. slot = lane>>4 (4 edge slots), q = lane&15 (16B chunk of 256B row).
// 4 edges per load instruction; unroll x4 => 16 edges / 4 x 1KB loads in flight.
// colsrc for the next iteration prefetched to break the colsrc->row chain.
__global__ __launch_bounds__(256, 8)
void aggx(const float* __restrict__ X, const int* __restrict__ colsrc,
          const int* __restrict__ rowptr, const float* __restrict__ dis,
          float* __restrict__ Y, float* __restrict__ rowsum) {
  int wid = threadIdx.x >> 6;
  int n = blockIdx.x * 4 + wid;
  int lane = threadIdx.x & 63;
  int slot = lane >> 4, q = lane & 15;
  float di = dis[n];
  int rp0 = rowptr[n];
  int m = rowptr[n + 1] - rp0 + 1;       // edges + self (self at index m-1)
  float4 acc = make_float4(0.f, 0.f, 0.f, 0.f);
  float wsum = 0.f;
  int s[4];
#pragma unroll
  for (int j = 0; j < 4; j++) {
    int idx = 4 * j + slot;
    s[j] = (idx >= m - 1) ? n : colsrc[rp0 + idx];
  }
  int p = 0;
  for (; p + 15 < m; p += 16) {
    int sn[4];
#pragma unroll
    for (int j = 0; j < 4; j++) {
      int idx = p + 16 + 4 * j + slot;
      sn[j] = (idx >= m - 1) ? n : colsrc[rp0 + idx];
    }
    float w[4]; float4 h[4];
#pragma unroll
    for (int j = 0; j < 4; j++) {
      w[j] = dis[s[j]] * di;
      h[j] = *reinterpret_cast<const float4*>(&X[(size_t)s[j] * FIN + q * 4]);
    }
#pragma unroll
    for (int j = 0; j < 4; j++) {
      acc.x = fmaf(h[j].x, w[j], acc.x);
      acc.y = fmaf(h[j].y, w[j], acc.y);
      acc.z = fmaf(h[j].z, w[j], acc.z);
      acc.w = fmaf(h[j].w, w[j], acc.w);
      wsum += w[j];
    }
#pragma unroll
    for (int j = 0; j < 4; j++) s[j] = sn[j];
  }
  for (; p < m; p += 4) {
    int idx = p + slot;
    if (idx < m) {
      int sv = (idx == m - 1) ? n : colsrc[rp0 + idx];
      float w = dis[sv] * di;
      float4 h = *reinterpret_cast<const float4*>(&X[(size_t)sv * FIN + q * 4]);
      acc.x = fmaf(h.x, w, acc.x);
      acc.y = fmaf(h.y, w, acc.y);
      acc.z = fmaf(h.z, w, acc.z);
      acc.w = fmaf(h.w, w, acc.w);
      wsum += w;
    }
  }
  // merge the 4 slots (lane pairs l^16 then l^32); all lanes end with full sums
  acc.x += __shfl_xor(acc.x, 16); acc.y += __shfl_xor(acc.y, 16);
  acc.z += __shfl_xor(acc.z, 16); acc.w += __shfl_xor(acc.w, 16);
  wsum  += __shfl_xor(wsum, 16);
  acc.x += __shfl_xor(acc.x, 32); acc.y += __shfl_xor(acc.y, 32);
  acc.z += __shfl_xor(acc.z, 32); acc.w += __shfl_xor(acc.w, 32);
  wsum  += __shfl_xor(wsum, 32);
  if (slot == 0) {
    *reinterpret_cast<float4*>(&Y[(size_t)n * FIN + q * 4]) = acc;
  }
  if (lane == 0) rowsum[n] = wsum;
}

// ---------------- h1 = Y@Wp + rowsum*c1 + gc1_b, fused LN1 stats ----------------
__global__ void gemmA(const float* __restrict__ Y, const float* __restrict__ Wp,
                      const float* __restrict__ c1, const float* __restrict__ gc1b,
                      const float* __restrict__ rowsum, const int* __restrict__ batch,
                      float* __restrict__ A, float* __restrict__ gsum, float* __restrict__ gsq) {
  __shared__ float ys[8 * 64];
  __shared__ float l1[8][2], l2[8][2];
  int n0 = blockIdx.x * 8, t = threadIdx.x;
  reinterpret_cast<float4*>(ys)[t] =
      reinterpret_cast<const float4*>(Y + (size_t)n0 * 64)[t];
  __syncthreads();
  float cv = c1[t], bv = gc1b[t];
  float acc[8];
#pragma unroll
  for (int n = 0; n < 8; n++) acc[n] = bv;
#pragma unroll 4
  for (int k = 0; k < 64; k++) {
    float wv = Wp[k * 128 + t];
#pragma unroll
    for (int n = 0; n < 8; n++) acc[n] = fmaf(ys[n * 64 + k], wv, acc[n]);
  }
#pragma unroll
  for (int n = 0; n < 8; n++) {
    acc[n] = fmaf(rowsum[n0 + n], cv, acc[n]);
    A[(size_t)(n0 + n) * 128 + t] = acc[n];
  }
  int wid = t >> 6, lane = t & 63;
#pragma unroll
  for (int n = 0; n < 8; n++) {
    float s1v = acc[n], s2v = acc[n] * acc[n];
    for (int o = 32; o > 0; o >>= 1) {
      s1v += __shfl_down(s1v, o);
      s2v += __shfl_down(s2v, o);
    }
    if (lane == 0) { l1[n][wid] = s1v; l2[n][wid] = s2v; }
  }
  __syncthreads();
  if (t < 8) {
    int b = batch[n0 + t];
    atomicAdd(&gsum[b], l1[t][0] + l1[t][1]);
    atomicAdd(&gsq[b], l2[t][0] + l2[t][1]);
  }
}

// ---------------- [N,128] @ [128,128] with fused graph-LN + ReLU on load ----------------
template <bool LN>
__global__ void gemm128(const float* __restrict__ X, const float* __restrict__ W,
                        float* __restrict__ Y,
                        const int* __restrict__ batch,
                        const float* __restrict__ mean, const float* __restrict__ inv,
                        const float* __restrict__ gamma, const float* __restrict__ beta) {
  __shared__ float xs[8 * 128];
  int n0 = blockIdx.x * 8, t = threadIdx.x;
  const float* xb = X + (size_t)n0 * 128;
  if (LN) {
#pragma unroll
    for (int j = 0; j < 8; j++) {
      int node = n0 + j;
      int bb = batch[node];
      float v = xb[j * 128 + t];
      v = (v - mean[bb]) * inv[bb] * gamma[t] + beta[t];
      xs[j * 128 + t] = fmaxf(v, 0.f);
    }
  } else {
    for (int i = t; i < 1024; i += 128) xs[i] = xb[i];
  }
  __syncthreads();
  float acc[8];
#pragma unroll
  for (int n = 0; n < 8; n++) acc[n] = 0.f;
#pragma unroll 4
  for (int k = 0; k < 128; k++) {
    float wv = W[k * 128 + t];
#pragma unroll
    for (int n = 0; n < 8; n++) acc[n] = fmaf(xs[n * 128 + k], wv, acc[n]);
  }
#pragma unroll
  for (int n = 0; n < 8; n++) Y[(size_t)(n0 + n) * 128 + t] = acc[n];
}

// ---------------- layer-2 CSR aggregation (128-wide) + bias, fused per-graph stats ----------------
// One wave per node, half = lane>>5 (2 edge slots), q = lane&31 (16B chunk of 512B row).
// 2 edges per load; unroll x4 => 8 edges / 4 x 1KB loads in flight; colsrc prefetched.
__global__ __launch_bounds__(256, 8)
void aggk(const float* __restrict__ Hin, const int* __restrict__ colsrc,
          const int* __restrict__ rowptr, const float* __restrict__ dis,
          const float* __restrict__ bias, const int* __restrict__ batch,
          float* __restrict__ Yout, float* __restrict__ gsum, float* __restrict__ gsq) {
  int wid = threadIdx.x >> 6;
  int n = blockIdx.x * 4 + wid;          // NN % 4 == 0, always valid
  int lane = threadIdx.x & 63;
  int half = lane >> 5, q = lane & 31;
  float di = dis[n];
  int rp0 = rowptr[n];
  int m = rowptr[n + 1] - rp0 + 1;       // edges + self (self at index m-1)
  float4 acc = make_float4(0.f, 0.f, 0.f, 0.f);
  int s[4];
#pragma unroll
  for (int j = 0; j < 4; j++) {
    int idx = 2 * j + half;
    s[j] = (idx >= m - 1) ? n : colsrc[rp0 + idx];
  }
  int p = 0;
  for (; p + 7 < m; p += 8) {
    int sn[4];
#pragma unroll
    for (int j = 0; j < 4; j++) {
      int idx = p + 8 + 2 * j + half;
      sn[j] = (idx >= m - 1) ? n : colsrc[rp0 + idx];
    }
    float w[4]; float4 h[4];
#pragma unroll
    for (int j = 0; j < 4; j++) {
      w[j] = dis[s[j]] * di;
      h[j] = *reinterpret_cast<const float4*>(&Hin[(size_t)s[j] * HH + q * 4]);
    }
#pragma unroll
    for (int j = 0; j < 4; j++) {
      acc.x = fmaf(h[j].x, w[j], acc.x);
      acc.y = fmaf(h[j].y, w[j], acc.y);
      acc.z = fmaf(h[j].z, w[j], acc.z);
      acc.w = fmaf(h[j].w, w[j], acc.w);
    }
#pragma unroll
    for (int j = 0; j < 4; j++) s[j] = sn[j];
  }
  for (; p < m; p += 2) {
    int idx = p + half;
    if (idx < m) {
      int sv = (idx == m - 1) ? n : colsrc[rp0 + idx];
      float w = dis[sv] * di;
      float4 h = *reinterpret_cast<const float4*>(&Hin[(size_t)sv * HH + q * 4]);
      acc.x = fmaf(h.x, w, acc.x);
      acc.y = fmaf(h.y, w, acc.y);
      acc.z = fmaf(h.z, w, acc.z);
      acc.w = fmaf(h.w, w, acc.w);
    }
  }
  // merge the two halves (lane l <-> lane l^32)
  acc.x += __shfl_xor(acc.x, 32);
  acc.y += __shfl_xor(acc.y, 32);
  acc.z += __shfl_xor(acc.z, 32);
  acc.w += __shfl_xor(acc.w, 32);
  float4 bv = *reinterpret_cast<const float4*>(&bias[q * 4]);
  acc.x += bv.x; acc.y += bv.y; acc.z += bv.z; acc.w += bv.w;
  if (half == 0) {
    *reinterpret_cast<float4*>(&Yout[(size_t)n * HH + q * 4]) = acc;
  }
  // per-wave stats over lanes 0..31 (each channel once)
  float s1 = acc.x + acc.y + acc.z + acc.w;
  float s2 = acc.x * acc.x + acc.y * acc.y + acc.z * acc.z + acc.w * acc.w;
  for (int o = 16; o > 0; o >>= 1) {
    s1 += __shfl_down(s1, o);
    s2 += __shfl_down(s2, o);
  }
  if (lane == 0) {
    int b = batch[n];
    atomicAdd(&gsum[b], s1);
    atomicAdd(&gsq[b], s2);
  }
}

__global__ void lnfinal(const float* __restrict__ gsum, const float* __restrict__ gsq,
                        const int* __restrict__ counts,
                        float* __restrict__ mean, float* __restrict__ inv) {
  int g = blockIdx.x * 256 + threadIdx.x;
  if (g >= GG) return;
  float denom = fmaxf((float)counts[g] * (float)HH, 1.f);
  float m = gsum[g] / denom;
  float v = gsq[g] / denom - m * m;
  mean[g] = m;
  inv[g] = rsqrtf(fmaxf(v, 0.f) + EPSV);
}

// ---------------- LN2 + ReLU + mean-pool scatter ----------------
__global__ void poolk(const float* __restrict__ A, const int* __restrict__ batch,
                      const float* __restrict__ mean, const float* __restrict__ inv,
                      const float* __restrict__ gamma, const float* __restrict__ beta,
                      float* __restrict__ pooled) {
  int idx = blockIdx.x * 256 + threadIdx.x;
  if (idx >= NN * HH) return;
  int n = idx >> 7, ch = idx & 127;
  int b = batch[n];
  float v = (A[idx] - mean[b]) * inv[b] * gamma[ch] + beta[ch];
  v = fmaxf(v, 0.f);
  atomicAdd(&pooled[b * 128 + ch], v);
}

__global__ void finalk(const float* __restrict__ pooled, const int* __restrict__ counts,
                       const float* __restrict__ w, const float* __restrict__ b,
                       float* __restrict__ out) {
  int g = blockIdx.x, t = threadIdx.x;  // 128 threads
  float cnt = fmaxf((float)counts[g], 1.f);
  float v = pooled[g * 128 + t] / cnt * w[t];
  for (int o = 32; o > 0; o >>= 1) v += __shfl_down(v, o);
  __shared__ float l[2];
  if ((t & 63) == 0) l[t >> 6] = v;
  __syncthreads();
  if (t == 0) out[g] = l[0] + l[1] + b[0];
}

extern "C" void kernel_launch(void* const* d_in, const int* in_sizes, int n_in,
                              void* d_out, int out_size, void* d_ws, size_t ws_size,
                              hipStream_t stream) {
  const float* x = (const float*)d_in[0];
  const int* ei = (const int*)d_in[1];      // [2,E] flat; src = ei[0..E), dst = ei[E..2E)
  const int* batch = (const int*)d_in[2];
  const float* fc1_w = (const float*)d_in[3];
  const float* fc1_b = (const float*)d_in[4];
  const float* gc1_w = (const float*)d_in[5];
  const float* gc1_b = (const float*)d_in[6];
  const float* gn1_g = (const float*)d_in[7];
  const float* gn1_b = (const float*)d_in[8];
  const float* gc2_w = (const float*)d_in[9];
  const float* gc2_b = (const float*)d_in[10];
  const float* gn2_g = (const float*)d_in[11];
  const float* gn2_b = (const float*)d_in[12];
  const float* fc2_w = (const float*)d_in[13];
  const float* fc2_b = (const float*)d_in[14];
  float* out = (float*)d_out;

  char* p = (char*)d_ws;
  auto alloc = [&](size_t bytes) { void* r = (void*)p; p += ((bytes + 255) / 256) * 256; return r; };
  float* A = (float*)alloc((size_t)NN * HH * 4);
  float* B = (float*)alloc((size_t)NN * HH * 4);
  float* Yx = B;                                   // [N,64] alias: B is dead until gemm128
  int* colsrc = (int*)alloc((size_t)EE * 4);
  int* rowptr = (int*)alloc((size_t)(NN + 1) * 4);
  int* deg = (int*)alloc((size_t)NN * 4);
  int* cursor = (int*)alloc((size_t)NN * 4);
  float* dis = (float*)alloc((size_t)NN * 4);
  float* rowsum = (float*)alloc((size_t)NN * 4);
  int* counts = (int*)alloc((size_t)GG * 4);
  float* gsum1 = (float*)alloc((size_t)GG * 4);
  float* gsq1 = (float*)alloc((size_t)GG * 4);
  float* gsum2 = (float*)alloc((size_t)GG * 4);
  float* gsq2 = (float*)alloc((size_t)GG * 4);
  float* mean1 = (float*)alloc((size_t)GG * 4);
  float* inv1 = (float*)alloc((size_t)GG * 4);
  float* mean2 = (float*)alloc((size_t)GG * 4);
  float* inv2 = (float*)alloc((size_t)GG * 4);
  float* pooled = (float*)alloc((size_t)GG * HH * 4);
  float* Wp = (float*)alloc((size_t)64 * 128 * 4);
  float* c1 = (float*)alloc((size_t)128 * 4);
  int* bsum = (int*)alloc(1024);
  int* boff = (int*)alloc(1024);

  int nblk = (NN + SCHUNK - 1) / SCHUNK;

  initk<<<(NN + 255) / 256, 256, 0, stream>>>(deg, cursor, counts, gsum1, gsq1, gsum2, gsq2, pooled);
  countk<<<(EE + 255) / 256, 256, 0, stream>>>(ei, batch, deg, counts);
  disk<<<(NN + 255) / 256, 256, 0, stream>>>(deg, dis);
  scan1<<<nblk, 256, 0, stream>>>(deg, bsum);
  scan2<<<1, 64, 0, stream>>>(bsum, boff, rowptr, nblk);
  scan3<<<nblk, 256, 0, stream>>>(deg, boff, rowptr);
  scatterk<<<(EE + 255) / 256, 256, 0, stream>>>(ei, cursor, rowptr, colsrc);
  prepw<<<65, 128, 0, stream>>>(fc1_w, fc1_b, gc1_w, Wp, c1);

  aggx<<<NN / 4, 256, 0, stream>>>(x, colsrc, rowptr, dis, Yx, rowsum);
  gemmA<<<NN / 8, 128, 0, stream>>>(Yx, Wp, c1, gc1_b, rowsum, batch, A, gsum1, gsq1);
  lnfinal<<<(GG + 255) / 256, 256, 0, stream>>>(gsum1, gsq1, counts, mean1, inv1);
  gemm128<true><<<NN / 8, 128, 0, stream>>>(A, gc2_w, B, batch, mean1, inv1, gn1_g, gn1_b);
  aggk<<<NN / 4, 256, 0, stream>>>(B, colsrc, rowptr, dis, gc2_b, batch, A, gsum2, gsq2);
  lnfinal<<<(GG + 255) / 256, 256, 0, stream>>>(gsum2, gsq2, counts, mean2, inv2);
  poolk<<<(NN * HH + 255) / 256, 256, 0, stream>>>(A, batch, mean2, inv2, gn2_g, gn2_b, pooled);
  finalk<<<GG, 128, 0, stream>>>(pooled, counts, fc2_w, fc2_b, out);
}

// Round 9
// 946.236 us; speedup vs baseline: 1.5026x; 1.0988x over previous
//
#include <hip/hip_runtime.h>

#define NN 100000
#define EE 1600000
#define FIN 64
#define HH 128
#define GG 512
#define EPSV 1e-5f

__device__ __forceinline__ unsigned short f2bf(float f) {
  unsigned int u = __float_as_uint(f);
  u = (u + 0x7FFFu + ((u >> 16) & 1u)) >> 16;
  return (unsigned short)u;
}

// ---------------- init ----------------
__global__ void initk(int* deg, int* cursor, int* counts,
                      float* gsum1, float* gsq1, float* gsum2, float* gsq2,
                      float* pooled) {
  int i = blockIdx.x * 256 + threadIdx.x;
  if (i < NN) { deg[i] = 1; cursor[i] = 0; }          // self-loop contributes 1
  if (i < GG) { counts[i] = 0; gsum1[i] = 0.f; gsq1[i] = 0.f; gsum2[i] = 0.f; gsq2[i] = 0.f; }
  if (i < GG * HH) pooled[i] = 0.f;
}

// ---------------- x -> bf16 ----------------
__global__ void convx(const float* __restrict__ x, unsigned short* __restrict__ xb) {
  int i = blockIdx.x * 256 + threadIdx.x;   // one float4 per thread
  if (i >= NN * FIN / 4) return;
  float4 v = reinterpret_cast<const float4*>(x)[i];
  ushort4 o;
  o.x = f2bf(v.x); o.y = f2bf(v.y); o.z = f2bf(v.z); o.w = f2bf(v.w);
  reinterpret_cast<ushort4*>(xb)[i] = o;
}

// ---------------- degree + graph counts ----------------
__global__ void countk(const int* __restrict__ ei, const int* __restrict__ batch,
                       int* deg, int* counts) {
  int i = blockIdx.x * 256 + threadIdx.x;
  if (i < EE) atomicAdd(&deg[ei[EE + i]], 1);   // dst row of edge_index
  if (i < NN) atomicAdd(&counts[batch[i]], 1);
}

__global__ void disk(const int* __restrict__ deg, float* __restrict__ dis) {
  int i = blockIdx.x * 256 + threadIdx.x;
  if (i < NN) dis[i] = rsqrtf((float)deg[i]);   // deg >= 1 always (self loop)
}

// ---------------- exclusive scan of in-degree (deg-1) -> rowptr ----------------
#define SCHUNK 1024
__global__ void scan1(const int* __restrict__ deg, int* __restrict__ bsum) {
  __shared__ int red[256];
  int b = blockIdx.x, t = threadIdx.x;
  int base = b * SCHUNK + t * 4;
  int s = 0;
#pragma unroll
  for (int i = 0; i < 4; i++) { int idx = base + i; if (idx < NN) s += deg[idx] - 1; }
  red[t] = s; __syncthreads();
  for (int o = 128; o > 0; o >>= 1) { if (t < o) red[t] += red[t + o]; __syncthreads(); }
  if (t == 0) bsum[b] = red[0];
}

__global__ void scan2(const int* __restrict__ bsum, int* __restrict__ boff,
                      int* __restrict__ rowptr, int nblk) {
  if (threadIdx.x == 0 && blockIdx.x == 0) {
    int run = 0;
    for (int i = 0; i < nblk; i++) { boff[i] = run; run += bsum[i]; }
    rowptr[NN] = run;  // == EE
  }
}

__global__ void scan3(const int* __restrict__ deg, const int* __restrict__ boff,
                      int* __restrict__ rowptr) {
  __shared__ int sc[2][256];
  int b = blockIdx.x, t = threadIdx.x;
  int base = b * SCHUNK + t * 4;
  int v[4]; int s = 0;
#pragma unroll
  for (int i = 0; i < 4; i++) {
    int idx = base + i;
    v[i] = (idx < NN) ? (deg[idx] - 1) : 0;
    s += v[i];
  }
  int pp = 0;
  sc[0][t] = s; __syncthreads();
  for (int o = 1; o < 256; o <<= 1) {
    int val = sc[pp][t];
    if (t >= o) val += sc[pp][t - o];
    sc[pp ^ 1][t] = val; __syncthreads();
    pp ^= 1;
  }
  int excl = sc[pp][t] - s;
  int p = boff[b] + excl;
#pragma unroll
  for (int i = 0; i < 4; i++) {
    int idx = base + i;
    if (idx < NN) rowptr[idx] = p;
    p += v[i];
  }
}

__global__ void scatterk(const int* __restrict__ ei, int* cursor,
                         const int* __restrict__ rowptr, int* __restrict__ colsrc) {
  int e = blockIdx.x * 256 + threadIdx.x;
  if (e >= EE) return;
  int d = ei[EE + e];
  int pos = rowptr[d] + atomicAdd(&cursor[d], 1);
  colsrc[pos] = ei[e];
}

// ---------------- fold fc1 into gc1: Wp = fc1_w @ gc1_w  [64,128]; c1 = fc1_b @ gc1_w ----------------
__global__ void prepw(const float* __restrict__ fc1w, const float* __restrict__ fc1b,
                      const float* __restrict__ gc1w,
                      float* __restrict__ Wp, float* __restrict__ c1) {
  int k = blockIdx.x, t = threadIdx.x;
  if (k < 64) {
    float s = 0.f;
    for (int j = 0; j < 128; j++) s = fmaf(fc1w[k * 128 + j], gc1w[j * 128 + t], s);
    Wp[k * 128 + t] = s;
  } else {
    float s = 0.f;
    for (int j = 0; j < 128; j++) s = fmaf(fc1b[j], gc1w[j * 128 + t], s);
    c1[t] = s;
  }
}

// ---------------- layer-1 aggregation on bf16 x (64ch, 128B rows) + rowsum ----------------
// One wave per node. slot = lane>>3 (8 edge slots), q = lane&7 (16B chunk of row).
// 8 rows per load instruction; unroll x2 => 16 edges / 2 x 1KB loads in flight.
__global__ __launch_bounds__(256, 8)
void aggx(const unsigned short* __restrict__ X, const int* __restrict__ colsrc,
          const int* __restrict__ rowptr, const float* __restrict__ dis,
          float* __restrict__ Y, float* __restrict__ rowsum) {
  int wid = threadIdx.x >> 6;
  int n = blockIdx.x * 4 + wid;
  int lane = threadIdx.x & 63;
  int slot = lane >> 3, q = lane & 7;
  float di = dis[n];
  int rp0 = rowptr[n];
  int m = rowptr[n + 1] - rp0 + 1;       // edges + self (self at index m-1)
  float acc[8];
#pragma unroll
  for (int k = 0; k < 8; k++) acc[k] = 0.f;
  float wsum = 0.f;
  int p = 0;
  for (; p + 15 < m; p += 16) {
    int s[2]; float w[2]; uint4 h[2];
#pragma unroll
    for (int j = 0; j < 2; j++) {
      int idx = p + 8 * j + slot;
      s[j] = (idx == m - 1) ? n : colsrc[rp0 + idx];
    }
#pragma unroll
    for (int j = 0; j < 2; j++) {
      w[j] = dis[s[j]] * di;
      h[j] = reinterpret_cast<const uint4*>(X + (size_t)s[j] * FIN)[q];
    }
#pragma unroll
    for (int j = 0; j < 2; j++) {
      unsigned int u;
      u = h[j].x; acc[0] = fmaf(__uint_as_float(u << 16), w[j], acc[0]);
                  acc[1] = fmaf(__uint_as_float(u & 0xFFFF0000u), w[j], acc[1]);
      u = h[j].y; acc[2] = fmaf(__uint_as_float(u << 16), w[j], acc[2]);
                  acc[3] = fmaf(__uint_as_float(u & 0xFFFF0000u), w[j], acc[3]);
      u = h[j].z; acc[4] = fmaf(__uint_as_float(u << 16), w[j], acc[4]);
                  acc[5] = fmaf(__uint_as_float(u & 0xFFFF0000u), w[j], acc[5]);
      u = h[j].w; acc[6] = fmaf(__uint_as_float(u << 16), w[j], acc[6]);
                  acc[7] = fmaf(__uint_as_float(u & 0xFFFF0000u), w[j], acc[7]);
      wsum += w[j];
    }
  }
  for (; p < m; p += 8) {
    int idx = p + slot;
    if (idx < m) {
      int sv = (idx == m - 1) ? n : colsrc[rp0 + idx];
      float w = dis[sv] * di;
      uint4 h = reinterpret_cast<const uint4*>(X + (size_t)sv * FIN)[q];
      unsigned int u;
      u = h.x; acc[0] = fmaf(__uint_as_float(u << 16), w, acc[0]);
               acc[1] = fmaf(__uint_as_float(u & 0xFFFF0000u), w, acc[1]);
      u = h.y; acc[2] = fmaf(__uint_as_float(u << 16), w, acc[2]);
               acc[3] = fmaf(__uint_as_float(u & 0xFFFF0000u), w, acc[3]);
      u = h.z; acc[4] = fmaf(__uint_as_float(u << 16), w, acc[4]);
               acc[5] = fmaf(__uint_as_float(u & 0xFFFF0000u), w, acc[5]);
      u = h.w; acc[6] = fmaf(__uint_as_float(u << 16), w, acc[6]);
               acc[7] = fmaf(__uint_as_float(u & 0xFFFF0000u), w, acc[7]);
      wsum += w;
    }
  }
  // merge the 8 slots (xor 8,16,32); all lanes end with full sums for their q
#pragma unroll
  for (int o = 8; o <= 32; o <<= 1) {
#pragma unroll
    for (int k = 0; k < 8; k++) acc[k] += __shfl_xor(acc[k], o);
    wsum += __shfl_xor(wsum, o);
  }
  if (slot == 0) {
    float4 a = make_float4(acc[0], acc[1], acc[2], acc[3]);
    float4 b = make_float4(acc[4], acc[5], acc[6], acc[7]);
    reinterpret_cast<float4*>(&Y[(size_t)n * FIN + q * 8])[0] = a;
    reinterpret_cast<float4*>(&Y[(size_t)n * FIN + q * 8])[1] = b;
  }
  if (lane == 0) rowsum[n] = wsum;
}

// ---------------- h1 = Y@Wp + rowsum*c1 + gc1_b, fused LN1 stats ----------------
__global__ void gemmA(const float* __restrict__ Y, const float* __restrict__ Wp,
                      const float* __restrict__ c1, const float* __restrict__ gc1b,
                      const float* __restrict__ rowsum, const int* __restrict__ batch,
                      float* __restrict__ A, float* __restrict__ gsum, float* __restrict__ gsq) {
  __shared__ float ys[8 * 64];
  __shared__ float l1[8][2], l2[8][2];
  int n0 = blockIdx.x * 8, t = threadIdx.x;
  reinterpret_cast<float4*>(ys)[t] =
      reinterpret_cast<const float4*>(Y + (size_t)n0 * 64)[t];
  __syncthreads();
  float cv = c1[t], bv = gc1b[t];
  float acc[8];
#pragma unroll
  for (int n = 0; n < 8; n++) acc[n] = bv;
#pragma unroll 4
  for (int k = 0; k < 64; k++) {
    float wv = Wp[k * 128 + t];
#pragma unroll
    for (int n = 0; n < 8; n++) acc[n] = fmaf(ys[n * 64 + k], wv, acc[n]);
  }
#pragma unroll
  for (int n = 0; n < 8; n++) {
    acc[n] = fmaf(rowsum[n0 + n], cv, acc[n]);
    A[(size_t)(n0 + n) * 128 + t] = acc[n];
  }
  int wid = t >> 6, lane = t & 63;
#pragma unroll
  for (int n = 0; n < 8; n++) {
    float s1v = acc[n], s2v = acc[n] * acc[n];
    for (int o = 32; o > 0; o >>= 1) {
      s1v += __shfl_down(s1v, o);
      s2v += __shfl_down(s2v, o);
    }
    if (lane == 0) { l1[n][wid] = s1v; l2[n][wid] = s2v; }
  }
  __syncthreads();
  if (t < 8) {
    int b = batch[n0 + t];
    atomicAdd(&gsum[b], l1[t][0] + l1[t][1]);
    atomicAdd(&gsq[b], l2[t][0] + l2[t][1]);
  }
}

// ---------------- [N,128] @ [128,128] with fused graph-LN + ReLU on load; bf16 output ----------------
__global__ void gemm128(const float* __restrict__ X, const float* __restrict__ W,
                        unsigned short* __restrict__ Yb,
                        const int* __restrict__ batch,
                        const float* __restrict__ mean, const float* __restrict__ inv,
                        const float* __restrict__ gamma, const float* __restrict__ beta) {
  __shared__ float xs[8 * 128];
  int n0 = blockIdx.x * 8, t = threadIdx.x;
  const float* xb = X + (size_t)n0 * 128;
#pragma unroll
  for (int j = 0; j < 8; j++) {
    int node = n0 + j;
    int bb = batch[node];
    float v = xb[j * 128 + t];
    v = (v - mean[bb]) * inv[bb] * gamma[t] + beta[t];
    xs[j * 128 + t] = fmaxf(v, 0.f);
  }
  __syncthreads();
  float acc[8];
#pragma unroll
  for (int n = 0; n < 8; n++) acc[n] = 0.f;
#pragma unroll 4
  for (int k = 0; k < 128; k++) {
    float wv = W[k * 128 + t];
#pragma unroll
    for (int n = 0; n < 8; n++) acc[n] = fmaf(xs[n * 128 + k], wv, acc[n]);
  }
#pragma unroll
  for (int n = 0; n < 8; n++) Yb[(size_t)(n0 + n) * 128 + t] = f2bf(acc[n]);
}

// ---------------- layer-2 CSR aggregation on bf16 rows (128ch, 256B) + bias, fused stats ----------------
// One wave per node. slot = lane>>4 (4 edge slots), q = lane&15 (16B chunk of 256B row).
// 4 rows per load instruction; unroll x4 => 16 edges / 4 x 1KB loads in flight.
__global__ __launch_bounds__(256, 8)
void aggk(const unsigned short* __restrict__ Hin, const int* __restrict__ colsrc,
          const int* __restrict__ rowptr, const float* __restrict__ dis,
          const float* __restrict__ bias, const int* __restrict__ batch,
          float* __restrict__ Yout, float* __restrict__ gsum, float* __restrict__ gsq) {
  int wid = threadIdx.x >> 6;
  int n = blockIdx.x * 4 + wid;          // NN % 4 == 0, always valid
  int lane = threadIdx.x & 63;
  int slot = lane >> 4, q = lane & 15;
  float di = dis[n];
  int rp0 = rowptr[n];
  int m = rowptr[n + 1] - rp0 + 1;       // edges + self (self at index m-1)
  float acc[8];
#pragma unroll
  for (int k = 0; k < 8; k++) acc[k] = 0.f;
  int p = 0;
  for (; p + 15 < m; p += 16) {
    int s[4]; float w[4]; uint4 h[4];
#pragma unroll
    for (int j = 0; j < 4; j++) {
      int idx = p + 4 * j + slot;
      s[j] = (idx == m - 1) ? n : colsrc[rp0 + idx];
    }
#pragma unroll
    for (int j = 0; j < 4; j++) {
      w[j] = dis[s[j]] * di;
      h[j] = reinterpret_cast<const uint4*>(Hin + (size_t)s[j] * HH)[q];
    }
#pragma unroll
    for (int j = 0; j < 4; j++) {
      unsigned int u;
      u = h[j].x; acc[0] = fmaf(__uint_as_float(u << 16), w[j], acc[0]);
                  acc[1] = fmaf(__uint_as_float(u & 0xFFFF0000u), w[j], acc[1]);
      u = h[j].y; acc[2] = fmaf(__uint_as_float(u << 16), w[j], acc[2]);
                  acc[3] = fmaf(__uint_as_float(u & 0xFFFF0000u), w[j], acc[3]);
      u = h[j].z; acc[4] = fmaf(__uint_as_float(u << 16), w[j], acc[4]);
                  acc[5] = fmaf(__uint_as_float(u & 0xFFFF0000u), w[j], acc[5]);
      u = h[j].w; acc[6] = fmaf(__uint_as_float(u << 16), w[j], acc[6]);
                  acc[7] = fmaf(__uint_as_float(u & 0xFFFF0000u), w[j], acc[7]);
    }
  }
  for (; p < m; p += 4) {
    int idx = p + slot;
    if (idx < m) {
      int sv = (idx == m - 1) ? n : colsrc[rp0 + idx];
      float w = dis[sv] * di;
      uint4 h = reinterpret_cast<const uint4*>(Hin + (size_t)sv * HH)[q];
      unsigned int u;
      u = h.x; acc[0] = fmaf(__uint_as_float(u << 16), w, acc[0]);
               acc[1] = fmaf(__uint_as_float(u & 0xFFFF0000u), w, acc[1]);
      u = h.y; acc[2] = fmaf(__uint_as_float(u << 16), w, acc[2]);
               acc[3] = fmaf(__uint_as_float(u & 0xFFFF0000u), w, acc[3]);
      u = h.z; acc[4] = fmaf(__uint_as_float(u << 16), w, acc[4]);
               acc[5] = fmaf(__uint_as_float(u & 0xFFFF0000u), w, acc[5]);
      u = h.w; acc[6] = fmaf(__uint_as_float(u << 16), w, acc[6]);
               acc[7] = fmaf(__uint_as_float(u & 0xFFFF0000u), w, acc[7]);
    }
  }
  // merge the 4 slots (xor 16,32); all lanes end with full sums for their q
#pragma unroll
  for (int o = 16; o <= 32; o <<= 1) {
#pragma unroll
    for (int k = 0; k < 8; k++) acc[k] += __shfl_xor(acc[k], o);
  }
  float4 b0 = reinterpret_cast<const float4*>(&bias[q * 8])[0];
  float4 b1 = reinterpret_cast<const float4*>(&bias[q * 8])[1];
  acc[0] += b0.x; acc[1] += b0.y; acc[2] += b0.z; acc[3] += b0.w;
  acc[4] += b1.x; acc[5] += b1.y; acc[6] += b1.z; acc[7] += b1.w;
  if (slot == 0) {
    float4 a = make_float4(acc[0], acc[1], acc[2], acc[3]);
    float4 b = make_float4(acc[4], acc[5], acc[6], acc[7]);
    reinterpret_cast<float4*>(&Yout[(size_t)n * HH + q * 8])[0] = a;
    reinterpret_cast<float4*>(&Yout[(size_t)n * HH + q * 8])[1] = b;
  }
  // per-wave stats (lanes 0..15 hold channels q*8..q*8+7)
  float s1 = acc[0] + acc[1] + acc[2] + acc[3] + acc[4] + acc[5] + acc[6] + acc[7];
  float s2 = acc[0] * acc[0] + acc[1] * acc[1] + acc[2] * acc[2] + acc[3] * acc[3] +
             acc[4] * acc[4] + acc[5] * acc[5] + acc[6] * acc[6] + acc[7] * acc[7];
  for (int o = 8; o > 0; o >>= 1) {
    s1 += __shfl_down(s1, o);
    s2 += __shfl_down(s2, o);
  }
  if (lane == 0) {
    int b = batch[n];
    atomicAdd(&gsum[b], s1);
    atomicAdd(&gsq[b], s2);
  }
}

__global__ void lnfinal(const float* __restrict__ gsum, const float* __restrict__ gsq,
                        const int* __restrict__ counts,
                        float* __restrict__ mean, float* __restrict__ inv) {
  int g = blockIdx.x * 256 + threadIdx.x;
  if (g >= GG) return;
  float denom = fmaxf((float)counts[g] * (float)HH, 1.f);
  float m = gsum[g] / denom;
  float v = gsq[g] / denom - m * m;
  mean[g] = m;
  inv[g] = rsqrtf(fmaxf(v, 0.f) + EPSV);
}

// ---------------- LN2 + ReLU + mean-pool scatter ----------------
__global__ void poolk(const float* __restrict__ A, const int* __restrict__ batch,
                      const float* __restrict__ mean, const float* __restrict__ inv,
                      const float* __restrict__ gamma, const float* __restrict__ beta,
                      float* __restrict__ pooled) {
  int idx = blockIdx.x * 256 + threadIdx.x;
  if (idx >= NN * HH) return;
  int n = idx >> 7, ch = idx & 127;
  int b = batch[n];
  float v = (A[idx] - mean[b]) * inv[b] * gamma[ch] + beta[ch];
  v = fmaxf(v, 0.f);
  atomicAdd(&pooled[b * 128 + ch], v);
}

__global__ void finalk(const float* __restrict__ pooled, const int* __restrict__ counts,
                       const float* __restrict__ w, const float* __restrict__ b,
                       float* __restrict__ out) {
  int g = blockIdx.x, t = threadIdx.x;  // 128 threads
  float cnt = fmaxf((float)counts[g], 1.f);
  float v = pooled[g * 128 + t] / cnt * w[t];
  for (int o = 32; o > 0; o >>= 1) v += __shfl_down(v, o);
  __shared__ float l[2];
  if ((t & 63) == 0) l[t >> 6] = v;
  __syncthreads();
  if (t == 0) out[g] = l[0] + l[1] + b[0];
}

extern "C" void kernel_launch(void* const* d_in, const int* in_sizes, int n_in,
                              void* d_out, int out_size, void* d_ws, size_t ws_size,
                              hipStream_t stream) {
  const float* x = (const float*)d_in[0];
  const int* ei = (const int*)d_in[1];      // [2,E] flat; src = ei[0..E), dst = ei[E..2E)
  const int* batch = (const int*)d_in[2];
  const float* fc1_w = (const float*)d_in[3];
  const float* fc1_b = (const float*)d_in[4];
  const float* gc1_w = (const float*)d_in[5];
  const float* gc1_b = (const float*)d_in[6];
  const float* gn1_g = (const float*)d_in[7];
  const float* gn1_b = (const float*)d_in[8];
  const float* gc2_w = (const float*)d_in[9];
  const float* gc2_b = (const float*)d_in[10];
  const float* gn2_g = (const float*)d_in[11];
  const float* gn2_b = (const float*)d_in[12];
  const float* fc2_w = (const float*)d_in[13];
  const float* fc2_b = (const float*)d_in[14];
  float* out = (float*)d_out;

  char* p = (char*)d_ws;
  auto alloc = [&](size_t bytes) { void* r = (void*)p; p += ((bytes + 255) / 256) * 256; return r; };
  float* A = (float*)alloc((size_t)NN * HH * 4);
  float* B = (float*)alloc((size_t)NN * HH * 4);
  float* Yx = B;                                       // [N,64] fp32; B region reused
  unsigned short* Bb = (unsigned short*)B;             // [N,128] bf16; overwrites Yx after it's dead
  unsigned short* xb = (unsigned short*)(A + (size_t)NN * 96);  // [N,64] bf16 in tail of A (dead until gemmA)
  int* colsrc = (int*)alloc((size_t)EE * 4);
  int* rowptr = (int*)alloc((size_t)(NN + 1) * 4);
  int* deg = (int*)alloc((size_t)NN * 4);
  int* cursor = (int*)alloc((size_t)NN * 4);
  float* dis = (float*)alloc((size_t)NN * 4);
  float* rowsum = (float*)alloc((size_t)NN * 4);
  int* counts = (int*)alloc((size_t)GG * 4);
  float* gsum1 = (float*)alloc((size_t)GG * 4);
  float* gsq1 = (float*)alloc((size_t)GG * 4);
  float* gsum2 = (float*)alloc((size_t)GG * 4);
  float* gsq2 = (float*)alloc((size_t)GG * 4);
  float* mean1 = (float*)alloc((size_t)GG * 4);
  float* inv1 = (float*)alloc((size_t)GG * 4);
  float* mean2 = (float*)alloc((size_t)GG * 4);
  float* inv2 = (float*)alloc((size_t)GG * 4);
  float* pooled = (float*)alloc((size_t)GG * HH * 4);
  float* Wp = (float*)alloc((size_t)64 * 128 * 4);
  float* c1 = (float*)alloc((size_t)128 * 4);
  int* bsum = (int*)alloc(1024);
  int* boff = (int*)alloc(1024);

  int nblk = (NN + SCHUNK - 1) / SCHUNK;

  initk<<<(NN + 255) / 256, 256, 0, stream>>>(deg, cursor, counts, gsum1, gsq1, gsum2, gsq2, pooled);
  convx<<<(NN * FIN / 4 + 255) / 256, 256, 0, stream>>>(x, xb);
  countk<<<(EE + 255) / 256, 256, 0, stream>>>(ei, batch, deg, counts);
  disk<<<(NN + 255) / 256, 256, 0, stream>>>(deg, dis);
  scan1<<<nblk, 256, 0, stream>>>(deg, bsum);
  scan2<<<1, 64, 0, stream>>>(bsum, boff, rowptr, nblk);
  scan3<<<nblk, 256, 0, stream>>>(deg, boff, rowptr);
  scatterk<<<(EE + 255) / 256, 256, 0, stream>>>(ei, cursor, rowptr, colsrc);
  prepw<<<65, 128, 0, stream>>>(fc1_w, fc1_b, gc1_w, Wp, c1);

  aggx<<<NN / 4, 256, 0, stream>>>(xb, colsrc, rowptr, dis, Yx, rowsum);
  gemmA<<<NN / 8, 128, 0, stream>>>(Yx, Wp, c1, gc1_b, rowsum, batch, A, gsum1, gsq1);
  lnfinal<<<(GG + 255) / 256, 256, 0, stream>>>(gsum1, gsq1, counts, mean1, inv1);
  gemm128<<<NN / 8, 128, 0, stream>>>(A, gc2_w, Bb, batch, mean1, inv1, gn1_g, gn1_b);
  aggk<<<NN / 4, 256, 0, stream>>>(Bb, colsrc, rowptr, dis, gc2_b, batch, A, gsum2, gsq2);
  lnfinal<<<(GG + 255) / 256, 256, 0, stream>>>(gsum2, gsq2, counts, mean2, inv2);
  poolk<<<(NN * HH + 255) / 256, 256, 0, stream>>>(A, batch, mean2, inv2, gn2_g, gn2_b, pooled);
  finalk<<<GG, 128, 0, stream>>>(pooled, counts, fc2_w, fc2_b, out);
}